// Round 1
// baseline (5521.526 us; speedup 1.0000x reference)
//
#include <hip/hip_runtime.h>
#include <math.h>

#define B_   1024
#define T_   64
#define H_   512
#define V_   1024
#define GEN_ 100
#define FH   2048  // 4*H

// ---------------- workspace layout (bytes) ----------------
static constexpr size_t OFF_G    = 0;                                   // 2 * B*FH fp32 (split-K partials)
static constexpr size_t SZ_G     = 2ull * B_ * FH * 4;                  // 16 MB
static constexpr size_t OFF_H    = OFF_G + SZ_G;                        // B*H fp32
static constexpr size_t OFF_C    = OFF_H + (size_t)B_ * H_ * 4;         // B*H fp32
static constexpr size_t OFF_WIHT = OFF_C + (size_t)B_ * H_ * 4;         // V*FH fp32 (8 MB)
static constexpr size_t OFF_BSUM = OFF_WIHT + (size_t)V_ * FH * 4;      // FH fp32
static constexpr size_t OFF_TOK  = OFF_BSUM + (size_t)FH * 4;           // B int

__device__ __forceinline__ float sigf(float x) { return 1.0f / (1.0f + expf(-x)); }

// ---------------- setup kernels ----------------
__global__ __launch_bounds__(256) void k_init(const float* __restrict__ input,
                                              const float* __restrict__ Wh, const float* __restrict__ bh,
                                              const float* __restrict__ Wc, const float* __restrict__ bc,
                                              const float* __restrict__ bih, const float* __restrict__ bhh,
                                              float* __restrict__ hbuf, float* __restrict__ cbuf,
                                              float* __restrict__ bsum) {
    int idx = blockIdx.x * 256 + threadIdx.x;
    if (idx < B_ * H_) {
        int b = idx >> 9, j = idx & (H_ - 1);
        float x = input[b];
        hbuf[idx] = x * Wh[j] + bh[j];
        cbuf[idx] = x * Wc[j] + bc[j];
    }
    if (idx < FH) bsum[idx] = bih[idx] + bhh[idx];
}

__global__ __launch_bounds__(256) void k_tok0(const float* __restrict__ onehots, int* __restrict__ tok) {
    int idx = blockIdx.x * 256 + threadIdx.x;  // over B*V
    int b = idx >> 10, v = idx & (V_ - 1);
    if (onehots[(size_t)b * (T_ * V_) + v] > 0.5f) tok[b] = v;  // exact one-hot: single writer
}

__global__ __launch_bounds__(256) void k_transpose(const float* __restrict__ Wih, float* __restrict__ WihT) {
    int idx = blockIdx.x * 256 + threadIdx.x;  // over V*FH
    int v = idx >> 11, n = idx & (FH - 1);
    WihT[idx] = Wih[(size_t)n * V_ + v];
}

// ---------------- K1: g_partial[ks] = h @ W_hh^T (pure GEMM, split-K=2) ----------------
// grid (16 n-tiles, 8 m-tiles, 2 k-splits), 256 threads. BM=BN=128, BK=16, 8x8 micro-tile.
__global__ __launch_bounds__(256) void k_gates(const float* __restrict__ hbuf,
                                               const float* __restrict__ Whh,
                                               float* __restrict__ gpart) {
    const int tid = threadIdx.x;
    const int n0 = blockIdx.x * 128;
    const int m0 = blockIdx.y * 128;
    const int k0 = blockIdx.z * 256;
    float* __restrict__ gout = gpart + (size_t)blockIdx.z * (B_ * FH);

    __shared__ float Ast[16][132];  // [k][m], pad keeps 16B row alignment (132*4=528=33*16)
    __shared__ float Bst[16][132];  // [k][n]

    float acc[8][8];
#pragma unroll
    for (int i = 0; i < 8; i++)
#pragma unroll
        for (int j = 0; j < 8; j++) acc[i][j] = 0.0f;

    const int f4 = tid & 3;        // which float4 of the 16 k-columns
    const int ldrow = tid >> 2;    // 0..63
    const int tx = tid & 15, ty = tid >> 4;

    for (int cc = 0; cc < 16; cc++) {
        const int kb = k0 + cc * 16;
#pragma unroll
        for (int u = 0; u < 2; u++) {
            const int r = ldrow + u * 64;
            float4 va = *(const float4*)&hbuf[(size_t)(m0 + r) * H_ + kb + f4 * 4];
            Ast[f4 * 4 + 0][r] = va.x; Ast[f4 * 4 + 1][r] = va.y;
            Ast[f4 * 4 + 2][r] = va.z; Ast[f4 * 4 + 3][r] = va.w;
            float4 vb = *(const float4*)&Whh[(size_t)(n0 + r) * H_ + kb + f4 * 4];
            Bst[f4 * 4 + 0][r] = vb.x; Bst[f4 * 4 + 1][r] = vb.y;
            Bst[f4 * 4 + 2][r] = vb.z; Bst[f4 * 4 + 3][r] = vb.w;
        }
        __syncthreads();
#pragma unroll
        for (int kk = 0; kk < 16; kk++) {
            float a[8], b[8];
            *(float4*)&a[0] = *(const float4*)&Ast[kk][ty * 4];
            *(float4*)&a[4] = *(const float4*)&Ast[kk][ty * 4 + 64];
            *(float4*)&b[0] = *(const float4*)&Bst[kk][tx * 4];
            *(float4*)&b[4] = *(const float4*)&Bst[kk][tx * 4 + 64];
#pragma unroll
            for (int i = 0; i < 8; i++)
#pragma unroll
                for (int j = 0; j < 8; j++) acc[i][j] += a[i] * b[j];
        }
        __syncthreads();
    }

#pragma unroll
    for (int g2 = 0; g2 < 2; g2++)
#pragma unroll
        for (int i = 0; i < 4; i++) {
            const int m = m0 + ty * 4 + g2 * 64 + i;
#pragma unroll
            for (int g = 0; g < 2; g++) {
                float4 o;
                o.x = acc[g2 * 4 + i][g * 4 + 0];
                o.y = acc[g2 * 4 + i][g * 4 + 1];
                o.z = acc[g2 * 4 + i][g * 4 + 2];
                o.w = acc[g2 * 4 + i][g * 4 + 3];
                *(float4*)&gout[(size_t)m * FH + n0 + tx * 4 + g * 64] = o;
            }
        }
}

// ---------------- K2: cell + head + log_softmax + argmax + output ----------------
// grid 256 blocks (4 batch rows each), 256 threads.
__global__ __launch_bounds__(256) void k_head(const float* __restrict__ gpart,
                                              float* __restrict__ cbuf, float* __restrict__ hbuf,
                                              const float* __restrict__ WihT, const float* __restrict__ bsum,
                                              int* __restrict__ tok,
                                              const float* __restrict__ W1, const float* __restrict__ b1,
                                              const float* __restrict__ W2, const float* __restrict__ b2,
                                              float* __restrict__ outt) {
    const int tid = threadIdx.x;
    const int b0 = blockIdx.x * 4;

    __shared__ float hs[4][512];
    __shared__ float pps[2][4][104];
    __shared__ float ps[4][104];
    __shared__ float red[4][4];
    __shared__ int  redi[4][4];

    const float* __restrict__ g0 = gpart;
    const float* __restrict__ g1 = gpart + (size_t)B_ * FH;

    // ---- phase 1: LSTM cell (adds W_ih gather + bias here; K1 partials summed deterministically)
    for (int idx = tid; idx < 4 * H_; idx += 256) {
        const int r = idx >> 9, j = idx & (H_ - 1);
        const int b = b0 + r;
        const int tk = tok[b];
        const float* __restrict__ wr = WihT + (size_t)tk * FH;
        const size_t base = (size_t)b * FH;
        float gi = g0[base + j]        + g1[base + j]        + wr[j]        + bsum[j];
        float gf = g0[base + 512 + j]  + g1[base + 512 + j]  + wr[512 + j]  + bsum[512 + j];
        float gg = g0[base + 1024 + j] + g1[base + 1024 + j] + wr[1024 + j] + bsum[1024 + j];
        float go = g0[base + 1536 + j] + g1[base + 1536 + j] + wr[1536 + j] + bsum[1536 + j];
        float co = cbuf[(size_t)b * H_ + j];
        float cn = sigf(gf) * co + sigf(gi) * tanhf(gg);
        float hn = sigf(go) * tanhf(cn);
        cbuf[(size_t)b * H_ + j] = cn;
        hbuf[(size_t)b * H_ + j] = hn;
        hs[r][j] = hn;
    }
    __syncthreads();

    // ---- phase 2: p = relu(h @ W1^T + b1), 200 jobs = (gen, k-half), each does all 4 rows
    if (tid < 200) {
        const int gi2 = tid % 100, kq = tid / 100;
        const float4* __restrict__ wrow = (const float4*)(W1 + (size_t)gi2 * H_ + kq * 256);
        float a0 = 0.f, a1 = 0.f, a2 = 0.f, a3 = 0.f;
        for (int k4 = 0; k4 < 64; k4++) {
            float4 w  = wrow[k4];
            float4 h0 = *(const float4*)&hs[0][kq * 256 + k4 * 4];
            float4 h1 = *(const float4*)&hs[1][kq * 256 + k4 * 4];
            float4 h2 = *(const float4*)&hs[2][kq * 256 + k4 * 4];
            float4 h3 = *(const float4*)&hs[3][kq * 256 + k4 * 4];
            a0 += w.x * h0.x + w.y * h0.y + w.z * h0.z + w.w * h0.w;
            a1 += w.x * h1.x + w.y * h1.y + w.z * h1.z + w.w * h1.w;
            a2 += w.x * h2.x + w.y * h2.y + w.z * h2.z + w.w * h2.w;
            a3 += w.x * h3.x + w.y * h3.y + w.z * h3.z + w.w * h3.w;
        }
        pps[kq][0][gi2] = a0; pps[kq][1][gi2] = a1;
        pps[kq][2][gi2] = a2; pps[kq][3][gi2] = a3;
    }
    __syncthreads();
    for (int idx = tid; idx < 400; idx += 256) {
        const int r = idx / 100, gi2 = idx % 100;
        float v = b1[gi2] + pps[0][r][gi2] + pps[1][r][gi2];
        ps[r][gi2] = v > 0.f ? v : 0.f;
    }
    __syncthreads();

    // ---- phase 3: logits = p @ W2^T + b2; each thread: 4 vocab rows x all 4 batch rows
    const int v0 = tid * 4;
    float accv[4][4];  // [vi][r]
#pragma unroll
    for (int vi = 0; vi < 4; vi++) {
        const float bb = b2[v0 + vi];
#pragma unroll
        for (int r = 0; r < 4; r++) accv[vi][r] = bb;
    }
    for (int j4 = 0; j4 < 25; j4++) {
        float4 p0 = *(const float4*)&ps[0][j4 * 4];
        float4 p1 = *(const float4*)&ps[1][j4 * 4];
        float4 p2 = *(const float4*)&ps[2][j4 * 4];
        float4 p3 = *(const float4*)&ps[3][j4 * 4];
#pragma unroll
        for (int vi = 0; vi < 4; vi++) {
            float4 w = *(const float4*)&W2[(size_t)(v0 + vi) * GEN_ + j4 * 4];
            accv[vi][0] += w.x * p0.x + w.y * p0.y + w.z * p0.z + w.w * p0.w;
            accv[vi][1] += w.x * p1.x + w.y * p1.y + w.z * p1.z + w.w * p1.w;
            accv[vi][2] += w.x * p2.x + w.y * p2.y + w.z * p2.z + w.w * p2.w;
            accv[vi][3] += w.x * p3.x + w.y * p3.y + w.z * p3.z + w.w * p3.w;
        }
    }

    // ---- per-row max + argmax (first-index tie-break, matching np.argmax)
    float lmax[4]; int lidx[4];
#pragma unroll
    for (int r = 0; r < 4; r++) {
        lmax[r] = accv[0][r]; lidx[r] = v0;
#pragma unroll
        for (int vi = 1; vi < 4; vi++)
            if (accv[vi][r] > lmax[r]) { lmax[r] = accv[vi][r]; lidx[r] = v0 + vi; }
    }
#pragma unroll
    for (int off = 32; off; off >>= 1) {
#pragma unroll
        for (int r = 0; r < 4; r++) {
            float ov = __shfl_xor(lmax[r], off);
            int   oi = __shfl_xor(lidx[r], off);
            if (ov > lmax[r] || (ov == lmax[r] && oi < lidx[r])) { lmax[r] = ov; lidx[r] = oi; }
        }
    }
    const int wv = tid >> 6, lane = tid & 63;
    if (lane == 0) {
#pragma unroll
        for (int r = 0; r < 4; r++) { red[r][wv] = lmax[r]; redi[r][wv] = lidx[r]; }
    }
    __syncthreads();
    float rmax[4]; int ridx[4];
#pragma unroll
    for (int r = 0; r < 4; r++) {
        rmax[r] = red[r][0]; ridx[r] = redi[r][0];
#pragma unroll
        for (int w = 1; w < 4; w++)
            if (red[r][w] > rmax[r] || (red[r][w] == rmax[r] && redi[r][w] < ridx[r])) {
                rmax[r] = red[r][w]; ridx[r] = redi[r][w];
            }
    }
    __syncthreads();  // before reusing red[]

    // ---- sum(exp(x - max))
    float ls[4];
#pragma unroll
    for (int r = 0; r < 4; r++)
        ls[r] = expf(accv[0][r] - rmax[r]) + expf(accv[1][r] - rmax[r]) +
                expf(accv[2][r] - rmax[r]) + expf(accv[3][r] - rmax[r]);
#pragma unroll
    for (int off = 32; off; off >>= 1) {
#pragma unroll
        for (int r = 0; r < 4; r++) ls[r] += __shfl_xor(ls[r], off);
    }
    if (lane == 0) {
#pragma unroll
        for (int r = 0; r < 4; r++) red[r][wv] = ls[r];
    }
    __syncthreads();
#pragma unroll
    for (int r = 0; r < 4; r++) {
        const float logZ = rmax[r] + logf(red[r][0] + red[r][1] + red[r][2] + red[r][3]);
        float4 o;
        o.x = accv[0][r] - logZ; o.y = accv[1][r] - logZ;
        o.z = accv[2][r] - logZ; o.w = accv[3][r] - logZ;
        *(float4*)&outt[(size_t)(b0 + r) * V_ + v0] = o;
    }
    if (tid == 0) {
        tok[b0 + 0] = ridx[0]; tok[b0 + 1] = ridx[1];
        tok[b0 + 2] = ridx[2]; tok[b0 + 3] = ridx[3];
    }
}

// ---------------- host ----------------
extern "C" void kernel_launch(void* const* d_in, const int* in_sizes, int n_in,
                              void* d_out, int out_size, void* d_ws, size_t ws_size,
                              hipStream_t stream) {
    const float* input   = (const float*)d_in[0];
    const float* onehots = (const float*)d_in[1];
    // d_in[2] digits (unused), d_in[3] teacher (==0, free-running path hardcoded)
    const float* Wh  = (const float*)d_in[4];
    const float* bh  = (const float*)d_in[5];
    const float* Wc  = (const float*)d_in[6];
    const float* bc  = (const float*)d_in[7];
    const float* Wih = (const float*)d_in[8];
    const float* Whh = (const float*)d_in[9];
    const float* bih = (const float*)d_in[10];
    const float* bhh = (const float*)d_in[11];
    const float* W1  = (const float*)d_in[12];
    const float* b1  = (const float*)d_in[13];
    const float* W2  = (const float*)d_in[14];
    const float* b2  = (const float*)d_in[15];
    float* out = (float*)d_out;

    char* ws = (char*)d_ws;
    float* gpart = (float*)(ws + OFF_G);
    float* hbuf  = (float*)(ws + OFF_H);
    float* cbuf  = (float*)(ws + OFF_C);
    float* WihT  = (float*)(ws + OFF_WIHT);
    float* bsum  = (float*)(ws + OFF_BSUM);
    int*   tok   = (int*)(ws + OFF_TOK);

    k_init<<<(B_ * H_) / 256, 256, 0, stream>>>(input, Wh, bh, Wc, bc, bih, bhh, hbuf, cbuf, bsum);
    k_tok0<<<(B_ * V_) / 256, 256, 0, stream>>>(onehots, tok);
    k_transpose<<<((size_t)V_ * FH) / 256, 256, 0, stream>>>(Wih, WihT);

    for (int t = 0; t < T_; t++) {
        k_gates<<<dim3(16, 8, 2), 256, 0, stream>>>(hbuf, Whh, gpart);
        k_head<<<B_ / 4, 256, 0, stream>>>(gpart, cbuf, hbuf, WihT, bsum, tok,
                                           W1, b1, W2, b2, out + (size_t)t * B_ * V_);
    }
}

// Round 2
// 4578.016 us; speedup vs baseline: 1.2061x; 1.2061x over previous
//
#include <hip/hip_runtime.h>
#include <math.h>

#define B_   1024
#define T_   64
#define H_   512
#define V_   1024
#define GEN_ 100
#define FH   2048   // 4*H
#define KC   1536   // 3*H concatenated-K for bf16x2 compensated GEMM

// ---------------- workspace layout (bytes) ----------------
static constexpr size_t MB = 1024ull * 1024;
static constexpr size_t OFF_G    = 0;            // 2 * B*FH fp32 split-K partials (16 MB)
static constexpr size_t OFF_C    = 16 * MB;      // B*H fp32 (2 MB)
static constexpr size_t OFF_WIHT = 18 * MB;      // V*FH fp32 (8 MB)
static constexpr size_t OFF_ACAT = 26 * MB;      // B*KC bf16 (3 MB)   [h_hi | h_hi | h_lo]
static constexpr size_t OFF_BCAT = 29 * MB;      // FH*KC bf16 (6 MB)  [W_hi | W_lo | W_hi]
static constexpr size_t OFF_BSUM = 35 * MB;      // FH fp32
static constexpr size_t OFF_TOK  = 35 * MB + 8192;  // B int

typedef __attribute__((ext_vector_type(8))) short short8v;
typedef __attribute__((ext_vector_type(4))) float f32x4;

__device__ __forceinline__ float sigf(float x) { return 1.0f / (1.0f + expf(-x)); }

__device__ __forceinline__ unsigned short f2bf(float f) {  // RNE fp32 -> bf16
    unsigned int u = __float_as_uint(f);
    return (unsigned short)((u + 0x7FFFu + ((u >> 16) & 1u)) >> 16);
}
__device__ __forceinline__ float bf2f(unsigned short b) {
    return __uint_as_float(((unsigned int)b) << 16);
}

__device__ __forceinline__ void gload16(const void* g, void* l) {
    __builtin_amdgcn_global_load_lds((const __attribute__((address_space(1))) void*)g,
                                     (__attribute__((address_space(3))) void*)l, 16, 0, 0);
}

// ---------------- setup kernels ----------------
__global__ __launch_bounds__(256) void k_init(const float* __restrict__ input,
                                              const float* __restrict__ Wh, const float* __restrict__ bh,
                                              const float* __restrict__ Wc, const float* __restrict__ bc,
                                              const float* __restrict__ bih, const float* __restrict__ bhh,
                                              float* __restrict__ cbuf, short* __restrict__ acat,
                                              float* __restrict__ bsum) {
    int idx = blockIdx.x * 256 + threadIdx.x;  // over B*H
    int b = idx >> 9, j = idx & (H_ - 1);
    float x = input[b];
    float h0 = x * Wh[j] + bh[j];
    cbuf[idx] = x * Wc[j] + bc[j];
    unsigned short hi = f2bf(h0);
    unsigned short lo = f2bf(h0 - bf2f(hi));
    short* ar = acat + (size_t)b * KC;
    ar[j] = (short)hi; ar[512 + j] = (short)hi; ar[1024 + j] = (short)lo;
    if (idx < FH) bsum[idx] = bih[idx] + bhh[idx];
}

__global__ __launch_bounds__(256) void k_tok0(const float* __restrict__ onehots, int* __restrict__ tok) {
    int idx = blockIdx.x * 256 + threadIdx.x;  // over B*V
    int b = idx >> 10, v = idx & (V_ - 1);
    if (onehots[(size_t)b * (T_ * V_) + v] > 0.5f) tok[b] = v;  // exact one-hot: single writer
}

__global__ __launch_bounds__(256) void k_transpose(const float* __restrict__ Wih, float* __restrict__ WihT) {
    int idx = blockIdx.x * 256 + threadIdx.x;  // over V*FH
    int v = idx >> 11, n = idx & (FH - 1);
    WihT[idx] = Wih[(size_t)n * V_ + v];
}

__global__ __launch_bounds__(256) void k_prep(const float* __restrict__ Whh, short* __restrict__ bcat) {
    int idx = blockIdx.x * 256 + threadIdx.x;  // over FH*H
    int n = idx >> 9, k = idx & (H_ - 1);
    float w = Whh[idx];
    unsigned short hi = f2bf(w);
    unsigned short lo = f2bf(w - bf2f(hi));
    short* br = bcat + (size_t)n * KC;
    br[k] = (short)hi; br[512 + k] = (short)lo; br[1024 + k] = (short)hi;
}

// ---------------- K1: gpart[z] = partial of Acat @ Bcat^T (bf16 MFMA, split-K=2) ----------------
// grid (16 n-tiles, 8 m-tiles, 2 k-splits), 256 threads = 4 waves, 128x128 tile, BK=64.
// LDS uses XOR chunk swizzle: slot(row, cs) holds global 16B-chunk k8 = cs ^ (row&7).
__global__ __launch_bounds__(256) void k_gates(const short* __restrict__ Acat,
                                               const short* __restrict__ Bcat,
                                               float* __restrict__ gpart) {
    const int tid = threadIdx.x;
    const int lane = tid & 63, w = tid >> 6;
    const int n0 = blockIdx.x * 128;
    const int m0 = blockIdx.y * 128;
    const int k0 = blockIdx.z * (KC / 2);
    float* __restrict__ gout = gpart + (size_t)blockIdx.z * (B_ * FH);

    __shared__ __align__(16) short As[128 * 64];  // 16 KB, [row][chunk] swizzled
    __shared__ __align__(16) short Bs[128 * 64];  // 16 KB

    f32x4 acc[4][4];
#pragma unroll
    for (int i = 0; i < 4; i++)
#pragma unroll
        for (int j = 0; j < 4; j++) acc[i][j] = (f32x4){0.f, 0.f, 0.f, 0.f};

    const int quad = lane >> 4, l15 = lane & 15;
    const int wm = (w >> 1) * 64, wn = (w & 1) * 64;

    // staging geometry: wave w stages rows [w*32, w*32+32) in 4 instrs of 8 rows
    const int srow = lane >> 3;                      // row within 8-row group
    const int schunk = (lane & 7) ^ srow;            // global 16B-chunk index (XOR swizzle)
    const size_t lanoff = (size_t)srow * KC + (size_t)schunk * 8;  // bf16 elements

    const short* aw = Acat + (size_t)(m0 + w * 32) * KC + k0 + lanoff;
    const short* bw = Bcat + (size_t)(n0 + w * 32) * KC + k0 + lanoff;
    short* lA = &As[w * 32 * 64];  // 32 rows * 64 shorts/row
    short* lB = &Bs[w * 32 * 64];

    // fragment row constants
    int raA[4], rxA[4], raB[4], rxB[4];
#pragma unroll
    for (int i = 0; i < 4; i++) {
        int rm = wm + i * 16 + l15; raA[i] = rm * 8; rxA[i] = rm & 7;
        int rn = wn + i * 16 + l15; raB[i] = rn * 8; rxB[i] = rn & 7;
    }

    for (int it = 0; it < (KC / 2) / 64; ++it) {
        const short* ga = aw + it * 64;
        const short* gb = bw + it * 64;
#pragma unroll
        for (int u = 0; u < 4; ++u) {
            gload16(ga + (size_t)(u * 8) * KC, lA + u * 512);
            gload16(gb + (size_t)(u * 8) * KC, lB + u * 512);
        }
        __syncthreads();
#pragma unroll
        for (int kh = 0; kh < 2; ++kh) {
            const int c = kh * 4 + quad;
            short8v av[4], bv[4];
#pragma unroll
            for (int i = 0; i < 4; i++) av[i] = *(const short8v*)&As[(raA[i] + (c ^ rxA[i])) * 8];
#pragma unroll
            for (int j = 0; j < 4; j++) bv[j] = *(const short8v*)&Bs[(raB[j] + (c ^ rxB[j])) * 8];
#pragma unroll
            for (int i = 0; i < 4; i++)
#pragma unroll
                for (int j = 0; j < 4; j++)
                    acc[i][j] = __builtin_amdgcn_mfma_f32_16x16x32_bf16(av[i], bv[j], acc[i][j], 0, 0, 0);
        }
        __syncthreads();
    }

    // epilogue: C/D layout col(n)=lane&15, row(m)=quad*4+reg  [m89-verified]
#pragma unroll
    for (int i = 0; i < 4; i++) {
        const int m = m0 + wm + i * 16 + quad * 4;
#pragma unroll
        for (int j = 0; j < 4; j++) {
            const int n = n0 + wn + j * 16 + l15;
            float* gp = gout + (size_t)m * FH + n;
#pragma unroll
            for (int r = 0; r < 4; r++) gp[(size_t)r * FH] = acc[i][j][r];
        }
    }
}

// ---------------- K2: cell + head + log_softmax + argmax + output ----------------
// grid 256 blocks (4 batch rows each), 256 threads.
__global__ __launch_bounds__(256) void k_head(const float* __restrict__ gpart,
                                              float* __restrict__ cbuf, short* __restrict__ acat,
                                              const float* __restrict__ WihT, const float* __restrict__ bsum,
                                              int* __restrict__ tok,
                                              const float* __restrict__ W1, const float* __restrict__ b1,
                                              const float* __restrict__ W2, const float* __restrict__ b2,
                                              float* __restrict__ outt) {
    const int tid = threadIdx.x;
    const int b0 = blockIdx.x * 4;

    __shared__ float hs[4][512];
    __shared__ float pps[2][4][104];
    __shared__ float ps[4][104];
    __shared__ float red[4][4];
    __shared__ int  redi[4][4];

    const float* __restrict__ g0 = gpart;
    const float* __restrict__ g1 = gpart + (size_t)B_ * FH;

    // ---- phase 1: LSTM cell; writes c (fp32) and next-step A_cat (bf16 hi/hi/lo)
    for (int idx = tid; idx < 4 * H_; idx += 256) {
        const int r = idx >> 9, j = idx & (H_ - 1);
        const int b = b0 + r;
        const int tk = tok[b];
        const float* __restrict__ wr = WihT + (size_t)tk * FH;
        const size_t base = (size_t)b * FH;
        float gi = g0[base + j]        + g1[base + j]        + wr[j]        + bsum[j];
        float gf = g0[base + 512 + j]  + g1[base + 512 + j]  + wr[512 + j]  + bsum[512 + j];
        float gg = g0[base + 1024 + j] + g1[base + 1024 + j] + wr[1024 + j] + bsum[1024 + j];
        float go = g0[base + 1536 + j] + g1[base + 1536 + j] + wr[1536 + j] + bsum[1536 + j];
        float co = cbuf[(size_t)b * H_ + j];
        float cn = sigf(gf) * co + sigf(gi) * tanhf(gg);
        float hn = sigf(go) * tanhf(cn);
        cbuf[(size_t)b * H_ + j] = cn;
        hs[r][j] = hn;
        unsigned short hi = f2bf(hn);
        unsigned short lo = f2bf(hn - bf2f(hi));
        short* ar = acat + (size_t)b * KC;
        ar[j] = (short)hi; ar[512 + j] = (short)hi; ar[1024 + j] = (short)lo;
    }
    __syncthreads();

    // ---- phase 2: p = relu(h @ W1^T + b1), 200 jobs = (gen, k-half), each does all 4 rows
    if (tid < 200) {
        const int gi2 = tid % 100, kq = tid / 100;
        const float4* __restrict__ wrow = (const float4*)(W1 + (size_t)gi2 * H_ + kq * 256);
        float a0 = 0.f, a1 = 0.f, a2 = 0.f, a3 = 0.f;
        for (int k4 = 0; k4 < 64; k4++) {
            float4 w  = wrow[k4];
            float4 h0 = *(const float4*)&hs[0][kq * 256 + k4 * 4];
            float4 h1 = *(const float4*)&hs[1][kq * 256 + k4 * 4];
            float4 h2 = *(const float4*)&hs[2][kq * 256 + k4 * 4];
            float4 h3 = *(const float4*)&hs[3][kq * 256 + k4 * 4];
            a0 += w.x * h0.x + w.y * h0.y + w.z * h0.z + w.w * h0.w;
            a1 += w.x * h1.x + w.y * h1.y + w.z * h1.z + w.w * h1.w;
            a2 += w.x * h2.x + w.y * h2.y + w.z * h2.z + w.w * h2.w;
            a3 += w.x * h3.x + w.y * h3.y + w.z * h3.z + w.w * h3.w;
        }
        pps[kq][0][gi2] = a0; pps[kq][1][gi2] = a1;
        pps[kq][2][gi2] = a2; pps[kq][3][gi2] = a3;
    }
    __syncthreads();
    for (int idx = tid; idx < 400; idx += 256) {
        const int r = idx / 100, gi2 = idx % 100;
        float v = b1[gi2] + pps[0][r][gi2] + pps[1][r][gi2];
        ps[r][gi2] = v > 0.f ? v : 0.f;
    }
    __syncthreads();

    // ---- phase 3: logits = p @ W2^T + b2; each thread: 4 vocab rows x all 4 batch rows
    const int v0 = tid * 4;
    float accv[4][4];  // [vi][r]
#pragma unroll
    for (int vi = 0; vi < 4; vi++) {
        const float bb = b2[v0 + vi];
#pragma unroll
        for (int r = 0; r < 4; r++) accv[vi][r] = bb;
    }
    for (int j4 = 0; j4 < 25; j4++) {
        float4 p0 = *(const float4*)&ps[0][j4 * 4];
        float4 p1 = *(const float4*)&ps[1][j4 * 4];
        float4 p2 = *(const float4*)&ps[2][j4 * 4];
        float4 p3 = *(const float4*)&ps[3][j4 * 4];
#pragma unroll
        for (int vi = 0; vi < 4; vi++) {
            float4 w = *(const float4*)&W2[(size_t)(v0 + vi) * GEN_ + j4 * 4];
            accv[vi][0] += w.x * p0.x + w.y * p0.y + w.z * p0.z + w.w * p0.w;
            accv[vi][1] += w.x * p1.x + w.y * p1.y + w.z * p1.z + w.w * p1.w;
            accv[vi][2] += w.x * p2.x + w.y * p2.y + w.z * p2.z + w.w * p2.w;
            accv[vi][3] += w.x * p3.x + w.y * p3.y + w.z * p3.z + w.w * p3.w;
        }
    }

    // ---- per-row max + argmax (first-index tie-break, matching np.argmax)
    float lmax[4]; int lidx[4];
#pragma unroll
    for (int r = 0; r < 4; r++) {
        lmax[r] = accv[0][r]; lidx[r] = v0;
#pragma unroll
        for (int vi = 1; vi < 4; vi++)
            if (accv[vi][r] > lmax[r]) { lmax[r] = accv[vi][r]; lidx[r] = v0 + vi; }
    }
#pragma unroll
    for (int off = 32; off; off >>= 1) {
#pragma unroll
        for (int r = 0; r < 4; r++) {
            float ov = __shfl_xor(lmax[r], off);
            int   oi = __shfl_xor(lidx[r], off);
            if (ov > lmax[r] || (ov == lmax[r] && oi < lidx[r])) { lmax[r] = ov; lidx[r] = oi; }
        }
    }
    const int wv = tid >> 6, lane = tid & 63;
    if (lane == 0) {
#pragma unroll
        for (int r = 0; r < 4; r++) { red[r][wv] = lmax[r]; redi[r][wv] = lidx[r]; }
    }
    __syncthreads();
    float rmax[4]; int ridx[4];
#pragma unroll
    for (int r = 0; r < 4; r++) {
        rmax[r] = red[r][0]; ridx[r] = redi[r][0];
#pragma unroll
        for (int w = 1; w < 4; w++)
            if (red[r][w] > rmax[r] || (red[r][w] == rmax[r] && redi[r][w] < ridx[r])) {
                rmax[r] = red[r][w]; ridx[r] = redi[r][w];
            }
    }
    __syncthreads();  // before reusing red[]

    // ---- sum(exp(x - max))
    float ls[4];
#pragma unroll
    for (int r = 0; r < 4; r++)
        ls[r] = expf(accv[0][r] - rmax[r]) + expf(accv[1][r] - rmax[r]) +
                expf(accv[2][r] - rmax[r]) + expf(accv[3][r] - rmax[r]);
#pragma unroll
    for (int off = 32; off; off >>= 1) {
#pragma unroll
        for (int r = 0; r < 4; r++) ls[r] += __shfl_xor(ls[r], off);
    }
    if (lane == 0) {
#pragma unroll
        for (int r = 0; r < 4; r++) red[r][wv] = ls[r];
    }
    __syncthreads();
#pragma unroll
    for (int r = 0; r < 4; r++) {
        const float logZ = rmax[r] + logf(red[r][0] + red[r][1] + red[r][2] + red[r][3]);
        float4 o;
        o.x = accv[0][r] - logZ; o.y = accv[1][r] - logZ;
        o.z = accv[2][r] - logZ; o.w = accv[3][r] - logZ;
        *(float4*)&outt[(size_t)(b0 + r) * V_ + v0] = o;
    }
    if (tid == 0) {
        tok[b0 + 0] = ridx[0]; tok[b0 + 1] = ridx[1];
        tok[b0 + 2] = ridx[2]; tok[b0 + 3] = ridx[3];
    }
}

// ---------------- host ----------------
extern "C" void kernel_launch(void* const* d_in, const int* in_sizes, int n_in,
                              void* d_out, int out_size, void* d_ws, size_t ws_size,
                              hipStream_t stream) {
    const float* input   = (const float*)d_in[0];
    const float* onehots = (const float*)d_in[1];
    // d_in[2] digits (unused), d_in[3] teacher (==0, free-running path hardcoded)
    const float* Wh  = (const float*)d_in[4];
    const float* bh  = (const float*)d_in[5];
    const float* Wc  = (const float*)d_in[6];
    const float* bc  = (const float*)d_in[7];
    const float* Wih = (const float*)d_in[8];
    const float* Whh = (const float*)d_in[9];
    const float* bih = (const float*)d_in[10];
    const float* bhh = (const float*)d_in[11];
    const float* W1  = (const float*)d_in[12];
    const float* b1  = (const float*)d_in[13];
    const float* W2  = (const float*)d_in[14];
    const float* b2  = (const float*)d_in[15];
    float* out = (float*)d_out;

    char* ws = (char*)d_ws;
    float* gpart = (float*)(ws + OFF_G);
    float* cbuf  = (float*)(ws + OFF_C);
    float* WihT  = (float*)(ws + OFF_WIHT);
    short* acat  = (short*)(ws + OFF_ACAT);
    short* bcat  = (short*)(ws + OFF_BCAT);
    float* bsum  = (float*)(ws + OFF_BSUM);
    int*   tok   = (int*)(ws + OFF_TOK);

    k_init<<<(B_ * H_) / 256, 256, 0, stream>>>(input, Wh, bh, Wc, bc, bih, bhh, cbuf, acat, bsum);
    k_tok0<<<(B_ * V_) / 256, 256, 0, stream>>>(onehots, tok);
    k_transpose<<<(V_ * FH) / 256, 256, 0, stream>>>(Wih, WihT);
    k_prep<<<(FH * H_) / 256, 256, 0, stream>>>(Whh, bcat);

    for (int t = 0; t < T_; t++) {
        k_gates<<<dim3(16, 8, 2), 256, 0, stream>>>(acat, bcat, gpart);
        k_head<<<B_ / 4, 256, 0, stream>>>(gpart, cbuf, acat, WihT, bsum, tok,
                                           W1, b1, W2, b2, out + (size_t)t * B_ * V_);
    }
}